// Round 4
// baseline (155.707 us; speedup 1.0000x reference)
//
#include <hip/hip_runtime.h>

// RankingLoss: B=16384 rows, D=1024 fp32, C=14 int32 labels -> scalar fp32.
//
// R4: delivery-BW model (~3.6 TB/s L2-level ceiling observed R1-R3).
// 16 threads/row, full-D register accumulation, ONE 4-step shuffle reduce
// per row (vs 72 DS ops/wave in R3). Imposter row r+1 reads dedup in L1
// (block step footprint ~8.7 KB << 32 KiB L1). __launch_bounds__(256,2)
// gives the compiler a 256-VGPR budget so the 64 independent loads per
// thread actually pipeline (R3's VGPR=32 re-serialized everything).

constexpr int D      = 1024;
constexpr int C      = 14;
constexpr int TPR    = 16;             // threads per row
constexpr int RPB    = 256 / TPR;      // 16 rows per block
constexpr int CHUNKS = D / 4 / TPR;    // 16 float4 per stream per thread

__device__ __forceinline__ float dot4(const float4 x, const float4 y) {
    return x.x * y.x + x.y * y.y + x.z * y.z + x.w * y.w;
}

__global__ __launch_bounds__(256, 2) void rank_phase1(
    const float* __restrict__ zi, const float* __restrict__ zt,
    const int* __restrict__ labels, float* __restrict__ partial, int B)
{
    const int t    = threadIdx.x;
    const int rsub = t >> 4;                  // row within block [0,16)
    const int csub = t & 15;                  // column slot      [0,16)
    const int row  = blockIdx.x * RPB + rsub;
    const int M    = B - 1;                   // B is a power of two
    const int nrow = (row + 1) & M;

    // Margins on leader lanes only; loads issued before the main stream so
    // their latency hides under it. Labels binary: row*C*4 = 56B, 8B-aligned.
    float margin = 0.f;
    if (csub == 0) {
        const int2* La = (const int2*)(labels + (size_t)row  * C);
        const int2* Lb = (const int2*)(labels + (size_t)nrow * C);
        int dv = 0, nv = 0;
        #pragma unroll
        for (int q = 0; q < C / 2; ++q) {
            const int2 x = La[q];
            const int2 y = Lb[q];
            dv += (x.x ^ y.x) + (x.y ^ y.y);
            nv += (x.x | y.x) + (x.y | y.y);
        }
        margin = (dv == 0) ? 0.f : fmaxf(0.5f, (float)dv / (float)nv);
    }

    const float4* Ar  = (const float4*)(zi + (size_t)row  * D);
    const float4* Br  = (const float4*)(zt + (size_t)row  * D);
    const float4* Ar1 = (const float4*)(zi + (size_t)nrow * D);
    const float4* Br1 = (const float4*)(zt + (size_t)nrow * D);

    float p = 0.f, ii = 0.f, it = 0.f;
    // 16 independent chunks x 4 independent loads: full-D register
    // accumulation, compiler free to keep many loads in flight.
    #pragma unroll
    for (int c = 0; c < CHUNKS; ++c) {
        const int idx = csub + TPR * c;       // 16 lanes -> 256B segment
        const float4 a  = Ar [idx];
        const float4 b  = Br [idx];
        const float4 a1 = Ar1[idx];           // L1 hit: row group rsub+1
        const float4 b1 = Br1[idx];           //   loads the same lines
        p  += dot4(a,  b);
        ii += dot4(a1, b);
        it += dot4(b1, a);
    }

    // One reduction per row: 4 shfl_xor steps within the 16-lane group.
    #pragma unroll
    for (int off = 1; off < TPR; off <<= 1) {
        p  += __shfl_xor(p,  off, 64);
        ii += __shfl_xor(ii, off, 64);
        it += __shfl_xor(it, off, 64);
    }

    __shared__ float sm[RPB];
    if (csub == 0)
        sm[rsub] = fmaxf(ii - p + margin, 0.f)
                 + fmaxf(it - p + margin, 0.f);
    __syncthreads();
    if (t == 0) {
        float s = 0.f;
        #pragma unroll
        for (int k = 0; k < RPB; ++k) s += sm[k];
        partial[blockIdx.x] = s;
    }
}

__global__ __launch_bounds__(256) void rank_phase2(
    const float* __restrict__ partial, float* __restrict__ out,
    int npart, float invB)
{
    float s = 0.f;
    for (int i = threadIdx.x; i < npart; i += 256) s += partial[i];
    #pragma unroll
    for (int off = 32; off > 0; off >>= 1) s += __shfl_down(s, off, 64);
    __shared__ float sm[4];
    if ((threadIdx.x & 63) == 0) sm[threadIdx.x >> 6] = s;
    __syncthreads();
    if (threadIdx.x == 0)
        out[0] = (sm[0] + sm[1] + sm[2] + sm[3]) * invB;
}

extern "C" void kernel_launch(void* const* d_in, const int* in_sizes, int n_in,
                              void* d_out, int out_size, void* d_ws, size_t ws_size,
                              hipStream_t stream) {
    const float* zi     = (const float*)d_in[0];
    const float* zt     = (const float*)d_in[1];
    const int*   labels = (const int*)d_in[2];
    float*       out    = (float*)d_out;
    float*       ws     = (float*)d_ws;

    const int B      = in_sizes[0] / D;  // 16384
    const int blocks = B / RPB;          // 1024

    rank_phase1<<<blocks, 256, 0, stream>>>(zi, zt, labels, ws, B);
    rank_phase2<<<1, 256, 0, stream>>>(ws, out, blocks, 1.0f / (float)B);
}

// Round 5
// 150.759 us; speedup vs baseline: 1.0328x; 1.0328x over previous
//
#include <hip/hip_runtime.h>

// RankingLoss: B=16384 rows, D=1024 fp32, C=14 int32 labels -> scalar fp32.
//
// R5: zero-duplication streaming + nontemporal loads.
// Invariant seen R1-R4: ~150 MB crosses L2 in ~46us (~3.6 TB/s) no matter
// the kernel structure -> shared-path ceiling, not latency. Test: eliminate
// all duplicate reads (imposter row r+1 values come from shfl_down(.,8)
// within the wave; 1/8 halo re-load at the row-group boundary) and mark the
// stream nontemporal so lines don't fight for L2 install.
//
// Layout: wave = 8 rows x 8 chunk-lanes (128B contiguous per row per load,
// line-exact). Block = 4 waves = same 8 rows x 4 D-quarters. 2048 blocks.

constexpr int D   = 1024;
constexpr int C   = 14;
constexpr int RPB = 8;            // rows per block
constexpr int CPR = D / 4;        // 256 float4 chunks per row

typedef float f4 __attribute__((ext_vector_type(4)));

__device__ __forceinline__ float dot4(const f4 x, const f4 y) {
    return x.x * y.x + x.y * y.y + x.z * y.z + x.w * y.w;
}

__device__ __forceinline__ f4 shfl_down4(const f4 v) {
    f4 r;
    r.x = __shfl_down(v.x, 8, 64);
    r.y = __shfl_down(v.y, 8, 64);
    r.z = __shfl_down(v.z, 8, 64);
    r.w = __shfl_down(v.w, 8, 64);
    return r;
}

__global__ __launch_bounds__(256) void rank_phase1(
    const float* __restrict__ zi, const float* __restrict__ zt,
    const int* __restrict__ labels, float* __restrict__ partial, int B)
{
    const int wave = threadIdx.x >> 6;
    const int lane = threadIdx.x & 63;
    const int r0   = blockIdx.x * RPB;
    const int M    = B - 1;               // B is a power of two

    const int row_off = lane >> 3;        // [0,8)
    const int cl      = lane & 7;         // chunk lane [0,8)
    const int row     = r0 + row_off;     // < B always
    const int hrow    = (r0 + RPB) & M;   // halo row (row 8 of the group)

    const f4* ZI = (const f4*)zi;
    const f4* ZT = (const f4*)zt;

    const int cb = wave * (CPR / 4);      // D-quarter base: 0,64,128,192

    float p = 0.f, ii = 0.f, it = 0.f;

    #pragma unroll
    for (int i = 0; i < CPR / 4 / 8; ++i) {     // 8 iterations
        const int c = cb + 8 * i + cl;
        // Each byte of zi/zt is loaded exactly once across the grid (mod
        // the 1/8 halo). Streaming hint: don't churn L2 install.
        const f4 a = __builtin_nontemporal_load(&ZI[(size_t)row * CPR + c]);
        const f4 b = __builtin_nontemporal_load(&ZT[(size_t)row * CPR + c]);

        f4 ha, hb;
        if (row_off == 7) {               // boundary lanes fetch row r0+8
            ha = __builtin_nontemporal_load(&ZI[(size_t)hrow * CPR + c]);
            hb = __builtin_nontemporal_load(&ZT[(size_t)hrow * CPR + c]);
        }

        f4 aN = shfl_down4(a);            // row r+1, same chunk (lane+8)
        f4 bN = shfl_down4(b);
        if (row_off == 7) { aN = ha; bN = hb; }

        p  += dot4(a,  b);                // paired   dot(zi[r],  zt[r])
        ii += dot4(aN, b);                // imp_img  dot(zi[r+1],zt[r])
        it += dot4(bN, a);                // imp_txt  dot(zt[r+1],zi[r])
    }

    // Reduce across the 8 chunk lanes of each row group.
    #pragma unroll
    for (int off = 1; off < 8; off <<= 1) {
        p  += __shfl_xor(p,  off, 64);
        ii += __shfl_xor(ii, off, 64);
        it += __shfl_xor(it, off, 64);
    }

    __shared__ float sm[4][RPB][3];
    if (cl == 0) {
        sm[wave][row_off][0] = p;
        sm[wave][row_off][1] = ii;
        sm[wave][row_off][2] = it;
    }
    __syncthreads();

    if (threadIdx.x < RPB) {              // lanes 0..7 of wave 0
        const int k = threadIdx.x;
        float ps = 0.f, is = 0.f, ts = 0.f;
        #pragma unroll
        for (int w = 0; w < 4; ++w) {     // sum the 4 D-quarters
            ps += sm[w][k][0];
            is += sm[w][k][1];
            ts += sm[w][k][2];
        }
        const int ra = r0 + k;
        const int rb = (ra + 1) & M;
        const int2* La = (const int2*)(labels + (size_t)ra * C);
        const int2* Lb = (const int2*)(labels + (size_t)rb * C);
        int dv = 0, nv = 0;
        #pragma unroll
        for (int q = 0; q < C / 2; ++q) { // binary labels
            const int2 x = La[q];
            const int2 y = Lb[q];
            dv += (x.x ^ y.x) + (x.y ^ y.y);
            nv += (x.x | y.x) + (x.y | y.y);
        }
        const float m = (dv == 0) ? 0.f
                                  : fmaxf(0.5f, (float)dv / (float)nv);
        float v = fmaxf(is - ps + m, 0.f) + fmaxf(ts - ps + m, 0.f);
        #pragma unroll
        for (int off = 1; off < RPB; off <<= 1)   // lanes 0..7 all active
            v += __shfl_xor(v, off, 64);
        if (k == 0) partial[blockIdx.x] = v;
    }
}

__global__ __launch_bounds__(256) void rank_phase2(
    const float* __restrict__ partial, float* __restrict__ out,
    int npart, float invB)
{
    float s = 0.f;
    for (int i = threadIdx.x; i < npart; i += 256) s += partial[i];
    #pragma unroll
    for (int off = 32; off > 0; off >>= 1) s += __shfl_down(s, off, 64);
    __shared__ float sm[4];
    if ((threadIdx.x & 63) == 0) sm[threadIdx.x >> 6] = s;
    __syncthreads();
    if (threadIdx.x == 0)
        out[0] = (sm[0] + sm[1] + sm[2] + sm[3]) * invB;
}

extern "C" void kernel_launch(void* const* d_in, const int* in_sizes, int n_in,
                              void* d_out, int out_size, void* d_ws, size_t ws_size,
                              hipStream_t stream) {
    const float* zi     = (const float*)d_in[0];
    const float* zt     = (const float*)d_in[1];
    const int*   labels = (const int*)d_in[2];
    float*       out    = (float*)d_out;
    float*       ws     = (float*)d_ws;

    const int B      = in_sizes[0] / D;  // 16384
    const int blocks = B / RPB;          // 2048 -> 8 blocks/CU

    rank_phase1<<<blocks, 256, 0, stream>>>(zi, zt, labels, ws, B);
    rank_phase2<<<1, 256, 0, stream>>>(ws, out, blocks, 1.0f / (float)B);
}